// Round 1
// baseline (1067.843 us; speedup 1.0000x reference)
//
#include <hip/hip_runtime.h>
#include <hip/hip_bf16.h>
#include <cstdint>

#define KDIM 1024
#define BDIM 8192
#define VDIM 2

// ---------------------------------------------------------------------------
// Kernel 1: MT[j][i] = M[i][j] where M = (I - A_lower)^{-1}, unit lower tri.
// One wave (64 lanes) per column j. m[r] on lane l holds M[j + r*64 + l][j].
// 2-wide lookahead: one shuffle-reduce round finalizes two rows.
// ---------------------------------------------------------------------------
__global__ __launch_bounds__(64) void invert_cols(const float* __restrict__ A,
                                                  float* __restrict__ MT) {
  const int j = blockIdx.x;
  const int lane = threadIdx.x;
  const int rem = KDIM - j;  // valid rel indices: [0, rem)
  float m[16];
#pragma unroll
  for (int r = 0; r < 16; ++r) m[r] = 0.f;
  if (lane == 0) m[0] = 1.f;  // diagonal

  // zero-fill the strictly-upper part of MT row j (i < j)
  for (int idx = lane; idx < j; idx += 64) MT[(size_t)j * KDIM + idx] = 0.f;

  // rel = 1 special case: m_{j+1} = A[j+1][j] * m_j = A[j+1][j]
  if (rem > 1) {
    float a10 = A[(size_t)(j + 1) * KDIM + j];
    if (lane == 1) m[0] = a10;
  }

#pragma unroll
  for (int ri = 0; ri < 16; ++ri) {
    for (int ii = (ri == 0 ? 2 : 0); ii < 64; ii += 2) {
      const int rel = ri * 64 + ii;
      if (rel >= rem) break;
      const int i = j + rel;
      const float* Ar0 = A + (size_t)i * KDIM + j;
      const bool has2 = (rel + 1 < rem);
      const float* Ar1 = Ar0 + KDIM;
      float acc0 = 0.f, acc1 = 0.f;
#pragma unroll
      for (int r = 0; r <= ri; ++r) {
        const int rk = r * 64 + lane;
        if (rk < rel) {
          const float mv = m[r];
          acc0 += Ar0[rk] * mv;
          if (has2) acc1 += Ar1[rk] * mv;
        }
      }
#pragma unroll
      for (int s = 1; s < 64; s <<= 1) {
        acc0 += __shfl_xor(acc0, s, 64);
        acc1 += __shfl_xor(acc1, s, 64);
      }
      const float mi0 = acc0;
      float a10 = 0.f;
      if (has2) a10 = Ar1[rel];  // A[i+1][i]
      const float mi1 = acc1 + a10 * mi0;
      if (lane == ii) m[ri] = mi0;
      if (has2 && lane == (ii + 1)) m[ri] = mi1;
    }
    const int relw = ri * 64 + lane;
    if (relw < rem) MT[(size_t)j * KDIM + j + relw] = m[ri];
  }
}

// ---------------------------------------------------------------------------
// Kernel 2: C[b][i] = sum_k Z[b][k] * MT[k][i]   (skips k-blocks where MT==0)
// 128x128 tile per WG (256 threads), 8x8 micro-tile, TK=64.
// Zs stored k-major (transposed) so A-fragment loads are ds_read_b128.
// ---------------------------------------------------------------------------
constexpr int LDT = 132;  // 128 + 4 pad, keeps float4 alignment, avoids conflicts

__global__ __launch_bounds__(256) void gemm_tri(const float* __restrict__ Z,
                                                const float* __restrict__ MT,
                                                float* __restrict__ C) {
  __shared__ float Zs[64][LDT];  // [k][b_local]
  __shared__ float Ms[64][LDT];  // [k][i_local]

  const int wg = blockIdx.x;
  const int t7 = wg & 7;
  const int ni = (t7 & 1) ? (7 - (t7 >> 1)) : (t7 >> 1);  // {0,7,1,6,2,5,3,4}
  const int xb = wg >> 3;
  const int b0 = xb * 128;
  const int i0 = ni * 128;

  const int tid = threadIdx.x;
  const int tm = tid >> 4;   // 0..15
  const int tn = tid & 15;   // 0..15
  const int c4 = tid & 15, rr = tid >> 4;    // Z staging
  const int c8 = tid & 31, kr8 = tid >> 5;   // M staging

  float acc[8][8];
#pragma unroll
  for (int a = 0; a < 8; ++a)
#pragma unroll
    for (int b = 0; b < 8; ++b) acc[a][b] = 0.f;

  const int nkb = 2 * (ni + 1);  // triangular skip: only k <= i0+127 needed
  for (int kb = 0; kb < nkb; ++kb) {
    const int k0 = kb * 64;
#pragma unroll
    for (int q = 0; q < 8; ++q) {
      const int row = rr + 16 * q;  // 0..127 (b_local)
      float4 zv = *(const float4*)(Z + (size_t)(b0 + row) * KDIM + k0 + 4 * c4);
      Zs[4 * c4 + 0][row] = zv.x;
      Zs[4 * c4 + 1][row] = zv.y;
      Zs[4 * c4 + 2][row] = zv.z;
      Zs[4 * c4 + 3][row] = zv.w;
      const int kr = kr8 + 8 * q;   // 0..63
      *(float4*)&Ms[kr][4 * c8] =
          *(const float4*)(MT + (size_t)(k0 + kr) * KDIM + i0 + 4 * c8);
    }
    __syncthreads();
#pragma unroll 4
    for (int k = 0; k < 64; ++k) {
      float4 a0 = *(const float4*)&Zs[k][4 * tm];
      float4 a1 = *(const float4*)&Zs[k][64 + 4 * tm];
      float4 b0v = *(const float4*)&Ms[k][4 * tn];
      float4 b1v = *(const float4*)&Ms[k][64 + 4 * tn];
      const float av[8] = {a0.x, a0.y, a0.z, a0.w, a1.x, a1.y, a1.z, a1.w};
      const float bv[8] = {b0v.x, b0v.y, b0v.z, b0v.w, b1v.x, b1v.y, b1v.z, b1v.w};
#pragma unroll
      for (int a = 0; a < 8; ++a)
#pragma unroll
        for (int b = 0; b < 8; ++b) acc[a][b] += av[a] * bv[b];
    }
    __syncthreads();
  }

#pragma unroll
  for (int a = 0; a < 8; ++a) {
    const int row = b0 + ((a < 4) ? (4 * tm + a) : (64 + 4 * tm + (a - 4)));
    float4 o0 = make_float4(acc[a][0], acc[a][1], acc[a][2], acc[a][3]);
    float4 o1 = make_float4(acc[a][4], acc[a][5], acc[a][6], acc[a][7]);
    *(float4*)(C + (size_t)row * KDIM + i0 + 4 * tn) = o0;
    *(float4*)(C + (size_t)row * KDIM + i0 + 64 + 4 * tn) = o1;
  }
}

// ---------------------------------------------------------------------------
// Kernel 3: per-sample rank-1 correction, in place on d_out.
// u[b,:] = g[b,:] + (v - g[b,t]) * MT[t,:]   (MT[t][t]==1 makes u[b,t]=v)
// ---------------------------------------------------------------------------
__global__ __launch_bounds__(256) void correction_k(
    const float* __restrict__ z, const int* __restrict__ tgt,
    const int* __restrict__ var, const float* __restrict__ means,
    const float* __restrict__ lsc, const float* __restrict__ MT,
    float* __restrict__ out) {
  const int b = blockIdx.x;
  const int t = tgt[b];
  if (t < 0) return;  // uniform exit: no intervention, g is already u
  const int v = var[b];
  const float mval = means[t * VDIM + v];
  const float sval = expf(lsc[t * VDIM + v]);
  const float zv = z[(size_t)b * KDIM + t];
  const float gt = out[(size_t)b * KDIM + t];
  const float coef = (mval + sval * zv) - gt;
  __syncthreads();  // everyone has read g[b,t] before column t is overwritten
  const int i = threadIdx.x * 4;
  float4 g = *(float4*)(out + (size_t)b * KDIM + i);
  float4 mt = *(const float4*)(MT + (size_t)t * KDIM + i);
  g.x += coef * mt.x;
  g.y += coef * mt.y;
  g.z += coef * mt.z;
  g.w += coef * mt.w;
  *(float4*)(out + (size_t)b * KDIM + i) = g;
}

// ---------------------------------------------------------------------------
extern "C" void kernel_launch(void* const* d_in, const int* in_sizes, int n_in,
                              void* d_out, int out_size, void* d_ws,
                              size_t ws_size, hipStream_t stream) {
  const float* z = (const float*)d_in[0];
  const int* tgt = (const int*)d_in[1];
  const int* var = (const int*)d_in[2];
  const float* A = (const float*)d_in[3];
  const float* means = (const float*)d_in[4];
  const float* lsc = (const float*)d_in[5];
  float* out = (float*)d_out;
  float* MT = (float*)d_ws;  // K*K floats = 4 MB

  hipLaunchKernelGGL(invert_cols, dim3(KDIM), dim3(64), 0, stream, A, MT);
  hipLaunchKernelGGL(gemm_tri, dim3((BDIM / 128) * (KDIM / 128)), dim3(256), 0,
                     stream, z, MT, out);
  hipLaunchKernelGGL(correction_k, dim3(BDIM), dim3(256), 0, stream, z, tgt,
                     var, means, lsc, MT, out);
}

// Round 2
// 448.521 us; speedup vs baseline: 2.3808x; 2.3808x over previous
//
#include <hip/hip_runtime.h>
#include <hip/hip_bf16.h>
#include <cstdint>

#define KDIM 1024
#define BDIM 8192
#define VDIM 2
#define NBLK 16  // KDIM / 64

// ---------------------------------------------------------------------------
// Kernel 1a: invert the 16 diagonal 64x64 unit-lower-triangular blocks.
// T_i = (I - A_ii)^{-1}. One WG of 64 threads per block; thread c computes
// column c with A_ii broadcast from LDS (all threads read the same address).
// Outputs: T  [i][r][c] row-major   (for row-wise mat-vec in kernel 1b)
//          Tt [i][c][r] col-major   (for contiguous column reads in 1b)
// ---------------------------------------------------------------------------
__global__ __launch_bounds__(64) void invert_diag(const float* __restrict__ A,
                                                  float* __restrict__ T,
                                                  float* __restrict__ Tt) {
  const int ib = blockIdx.x;       // diagonal block index
  const int c = threadIdx.x;       // my column
  const int base = ib * 64;

  __shared__ float As[64 * 64];    // A_ii, broadcast-read (same addr all lanes)
  __shared__ float Ts[64 * 68];    // transpose staging, stride 68 (16B-aligned)

  for (int r = 0; r < 64; ++r)
    As[r * 64 + c] = A[(size_t)(base + r) * KDIM + base + c];
  __syncthreads();

  float m[64];
#pragma unroll
  for (int r = 0; r < 64; ++r) m[r] = (r == c) ? 1.f : 0.f;

  // forward substitution: m[r] = sum_{i<r} A[r][i] * m[i]  (for r > c)
#pragma unroll
  for (int r = 1; r < 64; ++r) {
    float acc0 = 0.f, acc1 = 0.f;
#pragma unroll
    for (int i = 0; i < 64; ++i) {
      if (i >= r) break;
      if (i & 1) acc1 += As[r * 64 + i] * m[i];
      else       acc0 += As[r * 64 + i] * m[i];
    }
    const float v = acc0 + acc1;
    m[r] = (r > c) ? v : m[r];
  }

  // Tt: thread c owns a contiguous row of 64 floats
#pragma unroll
  for (int r = 0; r < 64; r += 4) {
    float4 v = make_float4(m[r], m[r + 1], m[r + 2], m[r + 3]);
    *(float4*)(Tt + (size_t)ib * 4096 + c * 64 + r) = v;
  }

  // T: transpose through LDS, then row-contiguous writes
#pragma unroll
  for (int r = 0; r < 64; ++r) Ts[r * 68 + c] = m[r];
  __syncthreads();
#pragma unroll
  for (int c4 = 0; c4 < 64; c4 += 4) {
    float4 v = *(float4*)(Ts + c * 68 + c4);
    *(float4*)(T + (size_t)ib * 4096 + c * 64 + c4) = v;
  }
}

// ---------------------------------------------------------------------------
// Kernel 1b: off-diagonal sweep. One wave per column j of M; advances 64 rows
// per block step: y = A[block-row i] * m  (per-lane row dots, m broadcast from
// LDS), then m_block = T_i * y. Writes MT[j][*] (= M[*][j]).
// ---------------------------------------------------------------------------
__global__ __launch_bounds__(64) void invert_off(const float* __restrict__ A,
                                                 const float* __restrict__ T,
                                                 const float* __restrict__ Tt,
                                                 float* __restrict__ MT) {
  const int j = blockIdx.x;
  const int r = threadIdx.x;       // lane = row-within-block
  const int jb = j >> 6;
  const int jo = j & 63;

  __shared__ float mcol[KDIM];
  __shared__ float yv[64];

  // zero-fill MT[j][0 .. 64*jb)
  const float4 z4 = make_float4(0.f, 0.f, 0.f, 0.f);
  for (int idx = 4 * r; idx < 64 * jb; idx += 256)
    *(float4*)(MT + (size_t)j * KDIM + idx) = z4;

  // diagonal block: column jo of T_jb (zeros above diag, 1 at diag)
  const float tv = Tt[(size_t)jb * 4096 + jo * 64 + r];
  mcol[64 * jb + r] = tv;
  MT[(size_t)j * KDIM + 64 * jb + r] = tv;
  __syncthreads();

  for (int i = jb + 1; i < NBLK; ++i) {
    // y[r] = sum_k A[64i+r][64jb + k] * mcol[64jb + k]
    const float* Ar = A + (size_t)(64 * i + r) * KDIM + 64 * jb;
    const float* mc = mcol + 64 * jb;
    const int L = 64 * (i - jb);  // multiple of 64
    float a0 = 0.f, a1 = 0.f, a2 = 0.f, a3 = 0.f;
    for (int k = 0; k < L; k += 16) {
      float4 x0 = *(const float4*)(Ar + k);
      float4 x1 = *(const float4*)(Ar + k + 4);
      float4 x2 = *(const float4*)(Ar + k + 8);
      float4 x3 = *(const float4*)(Ar + k + 12);
      float4 w0 = *(const float4*)(mc + k);
      float4 w1 = *(const float4*)(mc + k + 4);
      float4 w2 = *(const float4*)(mc + k + 8);
      float4 w3 = *(const float4*)(mc + k + 12);
      a0 += x0.x * w0.x + x0.y * w0.y + x0.z * w0.z + x0.w * w0.w;
      a1 += x1.x * w1.x + x1.y * w1.y + x1.z * w1.z + x1.w * w1.w;
      a2 += x2.x * w2.x + x2.y * w2.y + x2.z * w2.z + x2.w * w2.w;
      a3 += x3.x * w3.x + x3.y * w3.y + x3.z * w3.z + x3.w * w3.w;
    }
    yv[r] = (a0 + a1) + (a2 + a3);
    __syncthreads();

    // m_new[r] = sum_c T_i[r][c] * y[c]
    const float* Tr = T + (size_t)i * 4096 + r * 64;
    float s0 = 0.f, s1 = 0.f;
#pragma unroll
    for (int c = 0; c < 64; c += 8) {
      float4 t0 = *(const float4*)(Tr + c);
      float4 t1 = *(const float4*)(Tr + c + 4);
      float4 y0 = *(const float4*)(yv + c);
      float4 y1 = *(const float4*)(yv + c + 4);
      s0 += t0.x * y0.x + t0.y * y0.y + t0.z * y0.z + t0.w * y0.w;
      s1 += t1.x * y1.x + t1.y * y1.y + t1.z * y1.z + t1.w * y1.w;
    }
    const float mv = s0 + s1;
    mcol[64 * i + r] = mv;
    MT[(size_t)j * KDIM + 64 * i + r] = mv;
    __syncthreads();
  }
}

// ---------------------------------------------------------------------------
// Kernel 2: C[b][i] = sum_k Z[b][k] * MT[k][i]   (skips k-blocks where MT==0)
// 128x128 tile per WG (256 threads), 8x8 micro-tile, TK=64.
// ---------------------------------------------------------------------------
constexpr int LDT = 132;

__global__ __launch_bounds__(256) void gemm_tri(const float* __restrict__ Z,
                                                const float* __restrict__ MT,
                                                float* __restrict__ C) {
  __shared__ float Zs[64][LDT];
  __shared__ float Ms[64][LDT];

  const int wg = blockIdx.x;
  const int t7 = wg & 7;
  const int ni = (t7 & 1) ? (7 - (t7 >> 1)) : (t7 >> 1);
  const int xb = wg >> 3;
  const int b0 = xb * 128;
  const int i0 = ni * 128;

  const int tid = threadIdx.x;
  const int tm = tid >> 4;
  const int tn = tid & 15;
  const int c4 = tid & 15, rr = tid >> 4;
  const int c8 = tid & 31, kr8 = tid >> 5;

  float acc[8][8];
#pragma unroll
  for (int a = 0; a < 8; ++a)
#pragma unroll
    for (int b = 0; b < 8; ++b) acc[a][b] = 0.f;

  const int nkb = 2 * (ni + 1);
  for (int kb = 0; kb < nkb; ++kb) {
    const int k0 = kb * 64;
#pragma unroll
    for (int q = 0; q < 8; ++q) {
      const int row = rr + 16 * q;
      float4 zv = *(const float4*)(Z + (size_t)(b0 + row) * KDIM + k0 + 4 * c4);
      Zs[4 * c4 + 0][row] = zv.x;
      Zs[4 * c4 + 1][row] = zv.y;
      Zs[4 * c4 + 2][row] = zv.z;
      Zs[4 * c4 + 3][row] = zv.w;
      const int kr = kr8 + 8 * q;
      *(float4*)&Ms[kr][4 * c8] =
          *(const float4*)(MT + (size_t)(k0 + kr) * KDIM + i0 + 4 * c8);
    }
    __syncthreads();
#pragma unroll 4
    for (int k = 0; k < 64; ++k) {
      float4 a0 = *(const float4*)&Zs[k][4 * tm];
      float4 a1 = *(const float4*)&Zs[k][64 + 4 * tm];
      float4 b0v = *(const float4*)&Ms[k][4 * tn];
      float4 b1v = *(const float4*)&Ms[k][64 + 4 * tn];
      const float av[8] = {a0.x, a0.y, a0.z, a0.w, a1.x, a1.y, a1.z, a1.w};
      const float bv[8] = {b0v.x, b0v.y, b0v.z, b0v.w, b1v.x, b1v.y, b1v.z, b1v.w};
#pragma unroll
      for (int a = 0; a < 8; ++a)
#pragma unroll
        for (int b = 0; b < 8; ++b) acc[a][b] += av[a] * bv[b];
    }
    __syncthreads();
  }

#pragma unroll
  for (int a = 0; a < 8; ++a) {
    const int row = b0 + ((a < 4) ? (4 * tm + a) : (64 + 4 * tm + (a - 4)));
    float4 o0 = make_float4(acc[a][0], acc[a][1], acc[a][2], acc[a][3]);
    float4 o1 = make_float4(acc[a][4], acc[a][5], acc[a][6], acc[a][7]);
    *(float4*)(C + (size_t)row * KDIM + i0 + 4 * tn) = o0;
    *(float4*)(C + (size_t)row * KDIM + i0 + 64 + 4 * tn) = o1;
  }
}

// ---------------------------------------------------------------------------
// Kernel 3: per-sample rank-1 correction, in place on d_out.
// u[b,:] = g[b,:] + (v - g[b,t]) * MT[t,:]
// ---------------------------------------------------------------------------
__global__ __launch_bounds__(256) void correction_k(
    const float* __restrict__ z, const int* __restrict__ tgt,
    const int* __restrict__ var, const float* __restrict__ means,
    const float* __restrict__ lsc, const float* __restrict__ MT,
    float* __restrict__ out) {
  const int b = blockIdx.x;
  const int t = tgt[b];
  if (t < 0) return;
  const int v = var[b];
  const float mval = means[t * VDIM + v];
  const float sval = expf(lsc[t * VDIM + v]);
  const float zv = z[(size_t)b * KDIM + t];
  const float gt = out[(size_t)b * KDIM + t];
  const float coef = (mval + sval * zv) - gt;
  __syncthreads();
  const int i = threadIdx.x * 4;
  float4 g = *(float4*)(out + (size_t)b * KDIM + i);
  float4 mt = *(const float4*)(MT + (size_t)t * KDIM + i);
  g.x += coef * mt.x;
  g.y += coef * mt.y;
  g.z += coef * mt.z;
  g.w += coef * mt.w;
  *(float4*)(out + (size_t)b * KDIM + i) = g;
}

// ---------------------------------------------------------------------------
extern "C" void kernel_launch(void* const* d_in, const int* in_sizes, int n_in,
                              void* d_out, int out_size, void* d_ws,
                              size_t ws_size, hipStream_t stream) {
  const float* z = (const float*)d_in[0];
  const int* tgt = (const int*)d_in[1];
  const int* var = (const int*)d_in[2];
  const float* A = (const float*)d_in[3];
  const float* means = (const float*)d_in[4];
  const float* lsc = (const float*)d_in[5];
  float* out = (float*)d_out;
  float* MT = (float*)d_ws;  // K*K floats = 4 MB (proven to fit)

  // T / Tt live in the tail of d_out: consumed by invert_off BEFORE gemm_tri
  // overwrites d_out (stream-ordered). 2 * 16*64*64 floats = 512 KB.
  float* T = out + (size_t)out_size - 2 * NBLK * 4096;
  float* Tt = T + NBLK * 4096;

  hipLaunchKernelGGL(invert_diag, dim3(NBLK), dim3(64), 0, stream, A, T, Tt);
  hipLaunchKernelGGL(invert_off, dim3(KDIM), dim3(64), 0, stream, A, T, Tt, MT);
  hipLaunchKernelGGL(gemm_tri, dim3((BDIM / 128) * (KDIM / 128)), dim3(256), 0,
                     stream, z, MT, out);
  hipLaunchKernelGGL(correction_k, dim3(BDIM), dim3(256), 0, stream, z, tgt,
                     var, means, lsc, MT, out);
}

// Round 3
// 317.637 us; speedup vs baseline: 3.3618x; 1.4121x over previous
//
#include <hip/hip_runtime.h>
#include <hip/hip_bf16.h>
#include <cstdint>

#define KDIM 1024
#define BDIM 8192
#define VDIM 2
#define NBLK 16  // KDIM / 64

typedef __attribute__((ext_vector_type(8))) short short8;
typedef __attribute__((ext_vector_type(4))) float f32x4;

__device__ inline unsigned short f2bf(float x) {
  unsigned u = __builtin_bit_cast(unsigned, x);
  u = (u + 0x7FFFu + ((u >> 16) & 1u)) >> 16;
  return (unsigned short)u;
}

// ---------------------------------------------------------------------------
// Kernel 1a: invert the 16 diagonal 64x64 unit-lower-triangular blocks.
// T_i = (I - A_ii)^{-1}.  T row-major, Tt col-major.
// ---------------------------------------------------------------------------
__global__ __launch_bounds__(64) void invert_diag(const float* __restrict__ A,
                                                  float* __restrict__ T,
                                                  float* __restrict__ Tt) {
  const int ib = blockIdx.x;
  const int c = threadIdx.x;
  const int base = ib * 64;

  __shared__ float As[64 * 64];
  __shared__ float Ts[64 * 68];

  for (int r = 0; r < 64; ++r)
    As[r * 64 + c] = A[(size_t)(base + r) * KDIM + base + c];
  __syncthreads();

  float m[64];
#pragma unroll
  for (int r = 0; r < 64; ++r) m[r] = (r == c) ? 1.f : 0.f;

#pragma unroll
  for (int r = 1; r < 64; ++r) {
    float acc0 = 0.f, acc1 = 0.f;
#pragma unroll
    for (int i = 0; i < 64; ++i) {
      if (i >= r) break;
      if (i & 1) acc1 += As[r * 64 + i] * m[i];
      else       acc0 += As[r * 64 + i] * m[i];
    }
    const float v = acc0 + acc1;
    m[r] = (r > c) ? v : m[r];
  }

#pragma unroll
  for (int r = 0; r < 64; r += 4) {
    float4 v = make_float4(m[r], m[r + 1], m[r + 2], m[r + 3]);
    *(float4*)(Tt + (size_t)ib * 4096 + c * 64 + r) = v;
  }

#pragma unroll
  for (int r = 0; r < 64; ++r) Ts[r * 68 + c] = m[r];
  __syncthreads();
#pragma unroll
  for (int c4 = 0; c4 < 64; c4 += 4) {
    float4 v = *(float4*)(Ts + c * 68 + c4);
    *(float4*)(T + (size_t)ib * 4096 + c * 64 + c4) = v;
  }
}

// ---------------------------------------------------------------------------
// Kernel 1b v2: off-diagonal sweep, 4 waves per column j.
// Step i:  y = A[block-row i, cols 64jb..64i) * mcol   (k-split across waves)
//          m_block = T_i * y                            (redundant per wave)
// ---------------------------------------------------------------------------
__global__ __launch_bounds__(256) void invert_off(const float* __restrict__ A,
                                                  const float* __restrict__ T,
                                                  const float* __restrict__ Tt,
                                                  float* __restrict__ MT) {
  const int j = blockIdx.x;
  const int tid = threadIdx.x;
  const int w = tid >> 6;
  const int r = tid & 63;
  const int jb = j >> 6;
  const int jo = j & 63;

  __shared__ float mcol[KDIM];
  __shared__ float ypart[4][64];
  __shared__ float yfull[64];

  const float4 z4 = make_float4(0.f, 0.f, 0.f, 0.f);
  for (int idx = 4 * tid; idx < 64 * jb; idx += 1024)
    *(float4*)(MT + (size_t)j * KDIM + idx) = z4;

  if (w == 0) {
    const float tv = Tt[(size_t)jb * 4096 + jo * 64 + r];
    mcol[64 * jb + r] = tv;
    MT[(size_t)j * KDIM + 64 * jb + r] = tv;
  }
  __syncthreads();

  for (int i = jb + 1; i < NBLK; ++i) {
    const int L = 64 * (i - jb);
    const int Lq = L >> 2;  // per-wave k-chunk, multiple of 16
    const float* Ar = A + (size_t)(64 * i + r) * KDIM + 64 * jb + w * Lq;
    const float* mc = mcol + 64 * jb + w * Lq;
    float a0 = 0.f, a1 = 0.f, a2 = 0.f, a3 = 0.f;
    for (int k = 0; k < Lq; k += 16) {
      float4 x0 = *(const float4*)(Ar + k);
      float4 x1 = *(const float4*)(Ar + k + 4);
      float4 x2 = *(const float4*)(Ar + k + 8);
      float4 x3 = *(const float4*)(Ar + k + 12);
      float4 w0 = *(const float4*)(mc + k);
      float4 w1 = *(const float4*)(mc + k + 4);
      float4 w2 = *(const float4*)(mc + k + 8);
      float4 w3 = *(const float4*)(mc + k + 12);
      a0 += x0.x * w0.x + x0.y * w0.y + x0.z * w0.z + x0.w * w0.w;
      a1 += x1.x * w1.x + x1.y * w1.y + x1.z * w1.z + x1.w * w1.w;
      a2 += x2.x * w2.x + x2.y * w2.y + x2.z * w2.z + x2.w * w2.w;
      a3 += x3.x * w3.x + x3.y * w3.y + x3.z * w3.z + x3.w * w3.w;
    }
    ypart[w][r] = (a0 + a1) + (a2 + a3);
    __syncthreads();
    const float ys =
        ypart[0][r] + ypart[1][r] + ypart[2][r] + ypart[3][r];
    if (w == 0) yfull[r] = ys;
    __syncthreads();

    // redundant 64x64 matvec in every wave (identical results)
    const float* Tr = T + (size_t)i * 4096 + r * 64;
    float s0 = 0.f, s1 = 0.f;
#pragma unroll
    for (int c = 0; c < 64; c += 8) {
      float4 t0 = *(const float4*)(Tr + c);
      float4 t1 = *(const float4*)(Tr + c + 4);
      float4 y0 = *(const float4*)(yfull + c);
      float4 y1 = *(const float4*)(yfull + c + 4);
      s0 += t0.x * y0.x + t0.y * y0.y + t0.z * y0.z + t0.w * y0.w;
      s1 += t1.x * y1.x + t1.y * y1.y + t1.z * y1.z + t1.w * y1.w;
    }
    const float mv = s0 + s1;
    mcol[64 * i + r] = mv;  // all waves write the same value (benign)
    if (w == 0) MT[(size_t)j * KDIM + 64 * i + r] = mv;
  }
}

// ---------------------------------------------------------------------------
// Kernel 1c: Mbf[i][k] = bf16(MT[k][i])  — transpose+convert, 64x64 tiles.
// ---------------------------------------------------------------------------
__global__ __launch_bounds__(256) void mt2bf(const float* __restrict__ MT,
                                             unsigned short* __restrict__ Mbf) {
  const int ib = blockIdx.x & 15;
  const int jb = blockIdx.x >> 4;
  const int i0 = ib * 64, j0 = jb * 64;
  __shared__ float tile[64][65];

  const int tr = threadIdx.x >> 4;
  const int tc = threadIdx.x & 15;
#pragma unroll
  for (int p = 0; p < 4; ++p) {
    const int rj = p * 16 + tr;  // row of MT (= j index)
    float4 v = *(const float4*)(MT + (size_t)(j0 + rj) * KDIM + i0 + 4 * tc);
    tile[rj][4 * tc + 0] = v.x;
    tile[rj][4 * tc + 1] = v.y;
    tile[rj][4 * tc + 2] = v.z;
    tile[rj][4 * tc + 3] = v.w;
  }
  __syncthreads();
#pragma unroll
  for (int p = 0; p < 4; ++p) {
    const int il = p * 16 + tr;  // row of Mbf (= i index)
    ushort4 o;
    o.x = f2bf(tile[4 * tc + 0][il]);
    o.y = f2bf(tile[4 * tc + 1][il]);
    o.z = f2bf(tile[4 * tc + 2][il]);
    o.w = f2bf(tile[4 * tc + 3][il]);
    *(ushort4*)(Mbf + (size_t)(i0 + il) * KDIM + j0 + 4 * tc) = o;
  }
}

// ---------------------------------------------------------------------------
// Kernel 2: bf16 MFMA GEMM.  C[b][i] = sum_k Z[b][k] * Mbf[i][k]   (NT)
// 128x128 tile, 4 waves (2x2 of 64x64), BK=64, mfma_f32_16x16x32_bf16.
// Z converted fp32->bf16 inline during staging. Triangular k-skip.
// ---------------------------------------------------------------------------
#define LDB 72  // row stride in ushorts: 2-way-free fragment reads

__global__ __launch_bounds__(256) void gemm_mfma(
    const float* __restrict__ Z, const unsigned short* __restrict__ Mbf,
    float* __restrict__ C) {
  __shared__ unsigned short As[128][LDB];
  __shared__ unsigned short Bs[128][LDB];

  const int wg = blockIdx.x;
  const int t7 = wg & 7;
  const int ni = (t7 & 1) ? (7 - (t7 >> 1)) : (t7 >> 1);
  const int xb = wg >> 3;
  const int b0 = xb * 128;
  const int i0 = ni * 128;

  const int tid = threadIdx.x;
  const int w = tid >> 6;
  const int lane = tid & 63;
  const int wr = w >> 1, wc = w & 1;
  const int mlane = lane & 15;
  const int q = lane >> 4;

  const int rq = tid >> 4, kq = tid & 15;  // A staging map
  const int cb = tid >> 3, ck = tid & 7;   // B staging map

  f32x4 acc[4][4];
#pragma unroll
  for (int a = 0; a < 4; ++a)
#pragma unroll
    for (int b = 0; b < 4; ++b) acc[a][b] = (f32x4){0.f, 0.f, 0.f, 0.f};

  const int nkb = 2 * (ni + 1);  // k only up to i0+128 (triangular)
  for (int kb = 0; kb < nkb; ++kb) {
    const int k0 = kb * 64;
    // ---- stage A (Z tile, fp32 -> bf16) : 8 passes of 16 rows ----
#pragma unroll
    for (int p = 0; p < 8; ++p) {
      const int r = p * 16 + rq;
      float4 zv = *(const float4*)(Z + (size_t)(b0 + r) * KDIM + k0 + 4 * kq);
      ushort4 o;
      o.x = f2bf(zv.x);
      o.y = f2bf(zv.y);
      o.z = f2bf(zv.z);
      o.w = f2bf(zv.w);
      *(ushort4*)&As[r][4 * kq] = o;
    }
    // ---- stage B (Mbf tile, already bf16) : 4 passes of 32 cols ----
#pragma unroll
    for (int p = 0; p < 4; ++p) {
      const int c = p * 32 + cb;
      *(uint4*)&Bs[c][8 * ck] =
          *(const uint4*)(Mbf + (size_t)(i0 + c) * KDIM + k0 + 8 * ck);
    }
    __syncthreads();
    // ---- MFMA: 2 k-steps of 32 ----
#pragma unroll
    for (int ks = 0; ks < 2; ++ks) {
      const int kf = ks * 32 + q * 8;
      short8 av[4], bv[4];
#pragma unroll
      for (int a = 0; a < 4; ++a)
        av[a] = *(const short8*)&As[wr * 64 + 16 * a + mlane][kf];
#pragma unroll
      for (int b = 0; b < 4; ++b)
        bv[b] = *(const short8*)&Bs[wc * 64 + 16 * b + mlane][kf];
#pragma unroll
      for (int a = 0; a < 4; ++a)
#pragma unroll
        for (int b = 0; b < 4; ++b)
          acc[a][b] =
              __builtin_amdgcn_mfma_f32_16x16x32_bf16(av[a], bv[b], acc[a][b], 0, 0, 0);
    }
    __syncthreads();
  }

  // ---- epilogue: C/D layout col = lane&15, row = q*4 + reg ----
#pragma unroll
  for (int a = 0; a < 4; ++a) {
    const int row0 = b0 + wr * 64 + 16 * a + q * 4;
#pragma unroll
    for (int b = 0; b < 4; ++b) {
      const int col = i0 + wc * 64 + 16 * b + mlane;
      float* Cp = C + (size_t)row0 * KDIM + col;
      Cp[0 * KDIM] = acc[a][b][0];
      Cp[1 * KDIM] = acc[a][b][1];
      Cp[2 * KDIM] = acc[a][b][2];
      Cp[3 * KDIM] = acc[a][b][3];
    }
  }
}

// ---------------------------------------------------------------------------
// Kernel 3: per-sample rank-1 correction, in place on d_out.
// u[b,:] = g[b,:] + (v - g[b,t]) * MT[t,:]
// ---------------------------------------------------------------------------
__global__ __launch_bounds__(256) void correction_k(
    const float* __restrict__ z, const int* __restrict__ tgt,
    const int* __restrict__ var, const float* __restrict__ means,
    const float* __restrict__ lsc, const float* __restrict__ MT,
    float* __restrict__ out) {
  const int b = blockIdx.x;
  const int t = tgt[b];
  if (t < 0) return;
  const int v = var[b];
  const float mval = means[t * VDIM + v];
  const float sval = expf(lsc[t * VDIM + v]);
  const float zv = z[(size_t)b * KDIM + t];
  const float gt = out[(size_t)b * KDIM + t];
  const float coef = (mval + sval * zv) - gt;
  __syncthreads();
  const int i = threadIdx.x * 4;
  float4 g = *(float4*)(out + (size_t)b * KDIM + i);
  float4 mt = *(const float4*)(MT + (size_t)t * KDIM + i);
  g.x += coef * mt.x;
  g.y += coef * mt.y;
  g.z += coef * mt.z;
  g.w += coef * mt.w;
  *(float4*)(out + (size_t)b * KDIM + i) = g;
}

// ---------------------------------------------------------------------------
extern "C" void kernel_launch(void* const* d_in, const int* in_sizes, int n_in,
                              void* d_out, int out_size, void* d_ws,
                              size_t ws_size, hipStream_t stream) {
  const float* z = (const float*)d_in[0];
  const int* tgt = (const int*)d_in[1];
  const int* var = (const int*)d_in[2];
  const float* A = (const float*)d_in[3];
  const float* means = (const float*)d_in[4];
  const float* lsc = (const float*)d_in[5];
  float* out = (float*)d_out;

  float* MT = (float*)d_ws;                                  // 4 MB fp32
  unsigned short* Mbf = (unsigned short*)((char*)d_ws + (size_t)KDIM * KDIM * 4);  // 2 MB bf16

  // T / Tt live in the tail of d_out: fully consumed by invert_off before
  // gemm_mfma overwrites d_out (stream-ordered). 512 KB.
  float* T = out + (size_t)out_size - 2 * NBLK * 4096;
  float* Tt = T + NBLK * 4096;

  hipLaunchKernelGGL(invert_diag, dim3(NBLK), dim3(64), 0, stream, A, T, Tt);
  hipLaunchKernelGGL(invert_off, dim3(KDIM), dim3(256), 0, stream, A, T, Tt, MT);
  hipLaunchKernelGGL(mt2bf, dim3(NBLK * NBLK), dim3(256), 0, stream, MT, Mbf);
  hipLaunchKernelGGL(gemm_mfma, dim3((BDIM / 128) * (KDIM / 128)), dim3(256), 0,
                     stream, z, Mbf, out);
  hipLaunchKernelGGL(correction_k, dim3(BDIM), dim3(256), 0, stream, z, tgt,
                     var, means, lsc, MT, out);
}

// Round 4
// 281.467 us; speedup vs baseline: 3.7938x; 1.1285x over previous
//
#include <hip/hip_runtime.h>
#include <hip/hip_bf16.h>
#include <cstdint>

#define KDIM 1024
#define BDIM 8192
#define VDIM 2
#define NBLK 16  // KDIM / 64

typedef __attribute__((ext_vector_type(8))) short short8;
typedef __attribute__((ext_vector_type(4))) float f32x4;

__device__ inline unsigned short f2bf(float x) {
  unsigned u = __builtin_bit_cast(unsigned, x);
  u = (u + 0x7FFFu + ((u >> 16) & 1u)) >> 16;
  return (unsigned short)u;
}

// Scratch layout inside the Mbf region (floats): per-level P^T buffers
#define SCR_L1 0        //  8 * 64*64   = 32768
#define SCR_L2 32768    //  4 * 128*128 = 65536
#define SCR_L3 98304    //  2 * 256*256 = 131072
#define SCR_L4 229376   //  1 * 512*512 = 262144
#define SCR_TOTAL 491520

// ---------------------------------------------------------------------------
// Kernel 0: zero MT (4 MB) + P^T scratch (1.875 MB). atomicAdd targets.
// ---------------------------------------------------------------------------
__global__ __launch_bounds__(256) void zero_ws(float* __restrict__ MT,
                                               float* __restrict__ scr) {
  const float4 z4 = make_float4(0.f, 0.f, 0.f, 0.f);
  const int stride = gridDim.x * blockDim.x;
  for (int i = blockIdx.x * blockDim.x + threadIdx.x; i < KDIM * KDIM / 4;
       i += stride)
    *(float4*)(MT + 4 * (size_t)i) = z4;
  for (int i = blockIdx.x * blockDim.x + threadIdx.x; i < SCR_TOTAL / 4;
       i += stride)
    *(float4*)(scr + 4 * (size_t)i) = z4;
}

// ---------------------------------------------------------------------------
// Kernel 1: invert the 16 diagonal 64x64 unit-lower-triangular blocks,
// writing column c of T_ib directly into MT row (64ib+c), cols 64ib..64ib+64.
// ---------------------------------------------------------------------------
__global__ __launch_bounds__(64) void invert_diag(const float* __restrict__ A,
                                                  float* __restrict__ MT) {
  const int ib = blockIdx.x;
  const int c = threadIdx.x;
  const int base = ib * 64;

  __shared__ float As[64 * 64];
  for (int r = 0; r < 64; ++r)
    As[r * 64 + c] = A[(size_t)(base + r) * KDIM + base + c];
  __syncthreads();

  float m[64];
#pragma unroll
  for (int r = 0; r < 64; ++r) m[r] = (r == c) ? 1.f : 0.f;

#pragma unroll
  for (int r = 1; r < 64; ++r) {
    float acc0 = 0.f, acc1 = 0.f;
#pragma unroll
    for (int i = 0; i < 64; ++i) {
      if (i >= r) break;
      if (i & 1) acc1 += As[r * 64 + i] * m[i];
      else       acc0 += As[r * 64 + i] * m[i];
    }
    const float v = acc0 + acc1;
    m[r] = (r > c) ? v : m[r];
  }

  // MT[base+c][base+r] = m[r]  (column c of T = contiguous MT row segment)
#pragma unroll
  for (int r = 0; r < 64; r += 4) {
    float4 v = make_float4(m[r], m[r + 1], m[r + 2], m[r + 3]);
    *(float4*)(MT + (size_t)(base + c) * KDIM + base + r) = v;
  }
}

// ---------------------------------------------------------------------------
// Combine phase P: Pt[j][r] += sum_c MT[base+j][base+c] * A[base+h+r][base+c]
// (= (A21 * M11)^T).  64x64 tiles, 256 thr, 4x4 micro, split-K chunks of 64,
// atomic accumulation into zeroed scratch.
// grid = combines * t * t * t, t = h/64.
// ---------------------------------------------------------------------------
__global__ __launch_bounds__(256) void comb_p(const float* __restrict__ A,
                                              const float* __restrict__ MT,
                                              float* __restrict__ Pt, int h) {
  const int t = h >> 6;
  int b = blockIdx.x;
  const int kc = b % t; b /= t;
  const int rt = b % t; b /= t;
  const int jt = b % t; b /= t;
  const int c = b;
  const int base = c * 2 * h;

  __shared__ float Ls[64][68];
  __shared__ float Rs[64][68];

  const int tid = threadIdx.x;
  const int k4 = tid & 15;
  const int rw = tid >> 4;
#pragma unroll
  for (int p = 0; p < 4; ++p) {
    const int m = p * 16 + rw;
    float4 lv = *(const float4*)(MT + (size_t)(base + jt * 64 + m) * KDIM +
                                 base + kc * 64 + 4 * k4);
    Ls[4 * k4 + 0][m] = lv.x;
    Ls[4 * k4 + 1][m] = lv.y;
    Ls[4 * k4 + 2][m] = lv.z;
    Ls[4 * k4 + 3][m] = lv.w;
    float4 rv = *(const float4*)(A + (size_t)(base + h + rt * 64 + m) * KDIM +
                                 base + kc * 64 + 4 * k4);
    Rs[4 * k4 + 0][m] = rv.x;
    Rs[4 * k4 + 1][m] = rv.y;
    Rs[4 * k4 + 2][m] = rv.z;
    Rs[4 * k4 + 3][m] = rv.w;
  }
  __syncthreads();

  const int tm = tid >> 4;
  const int tn = tid & 15;
  float acc[4][4];
#pragma unroll
  for (int a = 0; a < 4; ++a)
#pragma unroll
    for (int bb = 0; bb < 4; ++bb) acc[a][bb] = 0.f;

#pragma unroll 4
  for (int k = 0; k < 64; ++k) {
    float4 av = *(const float4*)&Ls[k][4 * tm];
    float4 bv = *(const float4*)&Rs[k][4 * tn];
    const float aa[4] = {av.x, av.y, av.z, av.w};
    const float bb4[4] = {bv.x, bv.y, bv.z, bv.w};
#pragma unroll
    for (int a = 0; a < 4; ++a)
#pragma unroll
      for (int bb = 0; bb < 4; ++bb) acc[a][bb] += aa[a] * bb4[bb];
  }

  float* P0 = Pt + (size_t)c * h * h;
#pragma unroll
  for (int a = 0; a < 4; ++a)
#pragma unroll
    for (int bb = 0; bb < 4; ++bb)
      unsafeAtomicAdd(P0 + (size_t)(jt * 64 + 4 * tm + a) * h + rt * 64 + 4 * tn + bb,
                      acc[a][bb]);
}

// ---------------------------------------------------------------------------
// Combine phase Q: MT[base+j][base+h+r] += sum_c Pt[j][c] * MT[base+h+c][base+h+r]
// (= (M22 * P)^T = M21^T).
// ---------------------------------------------------------------------------
__global__ __launch_bounds__(256) void comb_q(float* __restrict__ MT,
                                              const float* __restrict__ Pt,
                                              int h) {
  const int t = h >> 6;
  int b = blockIdx.x;
  const int kc = b % t; b /= t;
  const int rt = b % t; b /= t;
  const int jt = b % t; b /= t;
  const int c = b;
  const int base = c * 2 * h;

  __shared__ float Ls[64][68];
  __shared__ float Rs[64][68];

  const int tid = threadIdx.x;
  const int k4 = tid & 15;
  const int rw = tid >> 4;
  const float* P0 = Pt + (size_t)c * h * h;
#pragma unroll
  for (int p = 0; p < 4; ++p) {
    const int m = p * 16 + rw;
    float4 lv = *(const float4*)(P0 + (size_t)(jt * 64 + m) * h + kc * 64 + 4 * k4);
    Ls[4 * k4 + 0][m] = lv.x;
    Ls[4 * k4 + 1][m] = lv.y;
    Ls[4 * k4 + 2][m] = lv.z;
    Ls[4 * k4 + 3][m] = lv.w;
    // direct (n-contiguous) staging of MT22
    const int kk = p * 16 + rw;
    *(float4*)&Rs[kk][4 * k4] =
        *(const float4*)(MT + (size_t)(base + h + kc * 64 + kk) * KDIM +
                         base + h + rt * 64 + 4 * k4);
  }
  __syncthreads();

  const int tm = tid >> 4;
  const int tn = tid & 15;
  float acc[4][4];
#pragma unroll
  for (int a = 0; a < 4; ++a)
#pragma unroll
    for (int bb = 0; bb < 4; ++bb) acc[a][bb] = 0.f;

#pragma unroll 4
  for (int k = 0; k < 64; ++k) {
    float4 av = *(const float4*)&Ls[k][4 * tm];
    float4 bv = *(const float4*)&Rs[k][4 * tn];
    const float aa[4] = {av.x, av.y, av.z, av.w};
    const float bb4[4] = {bv.x, bv.y, bv.z, bv.w};
#pragma unroll
    for (int a = 0; a < 4; ++a)
#pragma unroll
      for (int bb = 0; bb < 4; ++bb) acc[a][bb] += aa[a] * bb4[bb];
  }

#pragma unroll
  for (int a = 0; a < 4; ++a)
#pragma unroll
    for (int bb = 0; bb < 4; ++bb)
      unsafeAtomicAdd(MT + (size_t)(base + jt * 64 + 4 * tm + a) * KDIM +
                          base + h + rt * 64 + 4 * tn + bb,
                      acc[a][bb]);
}

// ---------------------------------------------------------------------------
// Kernel 1c: Mbf[i][k] = bf16(MT[k][i])  — transpose+convert, 64x64 tiles.
// ---------------------------------------------------------------------------
__global__ __launch_bounds__(256) void mt2bf(const float* __restrict__ MT,
                                             unsigned short* __restrict__ Mbf) {
  const int ib = blockIdx.x & 15;
  const int jb = blockIdx.x >> 4;
  const int i0 = ib * 64, j0 = jb * 64;
  __shared__ float tile[64][65];

  const int tr = threadIdx.x >> 4;
  const int tc = threadIdx.x & 15;
#pragma unroll
  for (int p = 0; p < 4; ++p) {
    const int rj = p * 16 + tr;
    float4 v = *(const float4*)(MT + (size_t)(j0 + rj) * KDIM + i0 + 4 * tc);
    tile[rj][4 * tc + 0] = v.x;
    tile[rj][4 * tc + 1] = v.y;
    tile[rj][4 * tc + 2] = v.z;
    tile[rj][4 * tc + 3] = v.w;
  }
  __syncthreads();
#pragma unroll
  for (int p = 0; p < 4; ++p) {
    const int il = p * 16 + tr;
    ushort4 o;
    o.x = f2bf(tile[4 * tc + 0][il]);
    o.y = f2bf(tile[4 * tc + 1][il]);
    o.z = f2bf(tile[4 * tc + 2][il]);
    o.w = f2bf(tile[4 * tc + 3][il]);
    *(ushort4*)(Mbf + (size_t)(i0 + il) * KDIM + j0 + 4 * tc) = o;
  }
}

// ---------------------------------------------------------------------------
// Kernel 2: bf16 MFMA GEMM.  C[b][i] = sum_k Z[b][k] * Mbf[i][k]   (NT)
// 128x128 tile, 4 waves (2x2 of 64x64), BK=64, mfma_f32_16x16x32_bf16.
// ---------------------------------------------------------------------------
#define LDB 72

__global__ __launch_bounds__(256) void gemm_mfma(
    const float* __restrict__ Z, const unsigned short* __restrict__ Mbf,
    float* __restrict__ C) {
  __shared__ unsigned short As[128][LDB];
  __shared__ unsigned short Bs[128][LDB];

  const int wg = blockIdx.x;
  const int t7 = wg & 7;
  const int ni = (t7 & 1) ? (7 - (t7 >> 1)) : (t7 >> 1);
  const int xb = wg >> 3;
  const int b0 = xb * 128;
  const int i0 = ni * 128;

  const int tid = threadIdx.x;
  const int w = tid >> 6;
  const int lane = tid & 63;
  const int wr = w >> 1, wc = w & 1;
  const int mlane = lane & 15;
  const int q = lane >> 4;

  const int rq = tid >> 4, kq = tid & 15;
  const int cb = tid >> 3, ck = tid & 7;

  f32x4 acc[4][4];
#pragma unroll
  for (int a = 0; a < 4; ++a)
#pragma unroll
    for (int b = 0; b < 4; ++b) acc[a][b] = (f32x4){0.f, 0.f, 0.f, 0.f};

  const int nkb = 2 * (ni + 1);
  for (int kb = 0; kb < nkb; ++kb) {
    const int k0 = kb * 64;
#pragma unroll
    for (int p = 0; p < 8; ++p) {
      const int r = p * 16 + rq;
      float4 zv = *(const float4*)(Z + (size_t)(b0 + r) * KDIM + k0 + 4 * kq);
      ushort4 o;
      o.x = f2bf(zv.x);
      o.y = f2bf(zv.y);
      o.z = f2bf(zv.z);
      o.w = f2bf(zv.w);
      *(ushort4*)&As[r][4 * kq] = o;
    }
#pragma unroll
    for (int p = 0; p < 4; ++p) {
      const int c = p * 32 + cb;
      *(uint4*)&Bs[c][8 * ck] =
          *(const uint4*)(Mbf + (size_t)(i0 + c) * KDIM + k0 + 8 * ck);
    }
    __syncthreads();
#pragma unroll
    for (int ks = 0; ks < 2; ++ks) {
      const int kf = ks * 32 + q * 8;
      short8 av[4], bv[4];
#pragma unroll
      for (int a = 0; a < 4; ++a)
        av[a] = *(const short8*)&As[wr * 64 + 16 * a + mlane][kf];
#pragma unroll
      for (int b = 0; b < 4; ++b)
        bv[b] = *(const short8*)&Bs[wc * 64 + 16 * b + mlane][kf];
#pragma unroll
      for (int a = 0; a < 4; ++a)
#pragma unroll
        for (int b = 0; b < 4; ++b)
          acc[a][b] =
              __builtin_amdgcn_mfma_f32_16x16x32_bf16(av[a], bv[b], acc[a][b], 0, 0, 0);
    }
    __syncthreads();
  }

#pragma unroll
  for (int a = 0; a < 4; ++a) {
    const int row0 = b0 + wr * 64 + 16 * a + q * 4;
#pragma unroll
    for (int b = 0; b < 4; ++b) {
      const int col = i0 + wc * 64 + 16 * b + mlane;
      float* Cp = C + (size_t)row0 * KDIM + col;
      Cp[0 * KDIM] = acc[a][b][0];
      Cp[1 * KDIM] = acc[a][b][1];
      Cp[2 * KDIM] = acc[a][b][2];
      Cp[3 * KDIM] = acc[a][b][3];
    }
  }
}

// ---------------------------------------------------------------------------
// Kernel 3: per-sample rank-1 correction, in place on d_out.
// ---------------------------------------------------------------------------
__global__ __launch_bounds__(256) void correction_k(
    const float* __restrict__ z, const int* __restrict__ tgt,
    const int* __restrict__ var, const float* __restrict__ means,
    const float* __restrict__ lsc, const float* __restrict__ MT,
    float* __restrict__ out) {
  const int b = blockIdx.x;
  const int t = tgt[b];
  if (t < 0) return;
  const int v = var[b];
  const float mval = means[t * VDIM + v];
  const float sval = expf(lsc[t * VDIM + v]);
  const float zv = z[(size_t)b * KDIM + t];
  const float gt = out[(size_t)b * KDIM + t];
  const float coef = (mval + sval * zv) - gt;
  __syncthreads();
  const int i = threadIdx.x * 4;
  float4 g = *(float4*)(out + (size_t)b * KDIM + i);
  float4 mt = *(const float4*)(MT + (size_t)t * KDIM + i);
  g.x += coef * mt.x;
  g.y += coef * mt.y;
  g.z += coef * mt.z;
  g.w += coef * mt.w;
  *(float4*)(out + (size_t)b * KDIM + i) = g;
}

// ---------------------------------------------------------------------------
extern "C" void kernel_launch(void* const* d_in, const int* in_sizes, int n_in,
                              void* d_out, int out_size, void* d_ws,
                              size_t ws_size, hipStream_t stream) {
  const float* z = (const float*)d_in[0];
  const int* tgt = (const int*)d_in[1];
  const int* var = (const int*)d_in[2];
  const float* A = (const float*)d_in[3];
  const float* means = (const float*)d_in[4];
  const float* lsc = (const float*)d_in[5];
  float* out = (float*)d_out;

  float* MT = (float*)d_ws;  // 4 MB fp32 (M^T = column-major M)
  float* scr = (float*)((char*)d_ws + (size_t)KDIM * KDIM * 4);  // 2 MB region
  unsigned short* Mbf = (unsigned short*)scr;  // reused after combines finish

  hipLaunchKernelGGL(zero_ws, dim3(128), dim3(256), 0, stream, MT, scr);
  hipLaunchKernelGGL(invert_diag, dim3(NBLK), dim3(64), 0, stream, A, MT);

  // recursive doubling: levels h = 64, 128, 256, 512
  const int scroff[4] = {SCR_L1, SCR_L2, SCR_L3, SCR_L4};
  for (int lv = 0; lv < 4; ++lv) {
    const int h = 64 << lv;
    const int t = h >> 6;
    const int combines = NBLK >> (lv + 1);
    const int grid = combines * t * t * t;
    hipLaunchKernelGGL(comb_p, dim3(grid), dim3(256), 0, stream, A, MT,
                       scr + scroff[lv], h);
    hipLaunchKernelGGL(comb_q, dim3(grid), dim3(256), 0, stream, MT,
                       scr + scroff[lv], h);
  }

  hipLaunchKernelGGL(mt2bf, dim3(NBLK * NBLK), dim3(256), 0, stream, MT, Mbf);
  hipLaunchKernelGGL(gemm_mfma, dim3((BDIM / 128) * (KDIM / 128)), dim3(256), 0,
                     stream, z, Mbf, out);
  hipLaunchKernelGGL(correction_k, dim3(BDIM), dim3(256), 0, stream, z, tgt,
                     var, means, lsc, MT, out);
}